// Round 13
// baseline (160.538 us; speedup 1.0000x reference)
//
#include <hip/hip_runtime.h>
#include <cstdint>

// EdgeConv on MI355X.
// msg_e = A[dst] + B[src], A = x@(W1-W2)+b, B = x@W2.
// agg[i] = A[i] + max_{e: dst=i} B[src_e];  out = relu(agg), 0 for isolated nodes.
// GEMM: bf16x3 MFMA + fused bucket histogram (split-grid).  [R12: neutral-OK]
// Bucket CSR with 4-NODE buckets (BSH=2).  bucket_max v4: BRANCHLESS masked
// pkmax selection (R12 post-mortem: v3's 16-way switch = branch tree, killed
// load pipelining; selection must be straight-line and scale with bucket size).
// key & mask trick: key=0 is identity of monotone-u16 max.

#define C_CH 128
#define HBLK 256          // histogram/scatter blocks
#define BSH 2             // nodes per bucket = 4
#define NPB 4             // 1<<BSH
#define BPAD 2560         // padded bucket count (>= NBq = 2500)
#define CHK 2048          // edge-stage chunk in bucket_max

typedef __attribute__((ext_vector_type(8))) short bf16x8;
typedef __attribute__((ext_vector_type(4))) float f32x4;
typedef __attribute__((ext_vector_type(4))) unsigned int u32x4;
typedef __attribute__((ext_vector_type(2))) unsigned short u16x2v;

static inline size_t align_up(size_t v, size_t a) { return (v + a - 1) & ~(a - 1); }

__device__ inline unsigned f2bf_bits(float f) {  // RNE float->bf16 bits
    unsigned u = __builtin_bit_cast(unsigned, f);
    return (u + 0x7FFFu + ((u >> 16) & 1u)) >> 16;
}
__device__ inline unsigned pkmax(unsigned a, unsigned b) {
    u16x2v av = __builtin_bit_cast(u16x2v, a), bv = __builtin_bit_cast(u16x2v, b);
    return __builtin_bit_cast(unsigned, __builtin_elementwise_max(av, bv));
}
// branchless: key masked to 0 (max-identity) unless edge targets node k.
// p is wave-uniform (from readfirstlane) -> masks are SGPR cselects.
__device__ inline void upd4(unsigned p, unsigned v,
                            unsigned& a0, unsigned& a1, unsigned& a2, unsigned& a3) {
    unsigned sgn = (v >> 15) & 0x00010001u;
    unsigned key = v ^ (0x80008000u | (sgn * 0x7FFFu));
    unsigned loc = p & (NPB - 1);
    unsigned m0 = (loc == 0) ? 0xFFFFFFFFu : 0u;
    unsigned m1 = (loc == 1) ? 0xFFFFFFFFu : 0u;
    unsigned m2 = (loc == 2) ? 0xFFFFFFFFu : 0u;
    unsigned m3 = (loc == 3) ? 0xFFFFFFFFu : 0u;
    a0 = pkmax(a0, key & m0);
    a1 = pkmax(a1, key & m1);
    a2 = pkmax(a2, key & m2);
    a3 = pkmax(a3, key & m3);
}

// ---- K1: split-grid: [0, GX*4) MFMA GEMM blocks; [GX*4, +HBLK) bucket hist ----
__global__ __launch_bounds__(256) void gemm_hist(const float* __restrict__ x,
                                                 const float* __restrict__ W,
                                                 const float* __restrict__ bias,
                                                 float* __restrict__ Aarr,
                                                 unsigned short* __restrict__ Bbf,
                                                 const int* __restrict__ dst,
                                                 int* __restrict__ T2,
                                                 int Nn, int E_, int chunk) {
    __shared__ unsigned short Wh[64][136];
    __shared__ unsigned short Wl[64][136];
    __shared__ int cnt[BPAD];
    int tid = threadIdx.x;
    int GX = (Nn + 63) >> 6;
    int bid = blockIdx.x;
    if (bid < GX * 4) {
        // ---------- GEMM (proven R7-R12) ----------
        int bx = bid % GX, by = bid / GX;
        int col0 = by * 64;
        bool isA = (col0 < C_CH);  // block-uniform
        for (int idx = tid; idx < 64 * 64; idx += 256) {
            int c = idx & 63, k = (idx >> 6) * 2;
            int gc = col0 + c;
            float w0, w1;
            if (isA) {
                w0 = W[k * C_CH + gc] - W[(k + C_CH) * C_CH + gc];
                w1 = W[(k + 1) * C_CH + gc] - W[(k + 1 + C_CH) * C_CH + gc];
            } else {
                int g2 = gc - C_CH;
                w0 = W[(k + C_CH) * C_CH + g2];
                w1 = W[(k + 1 + C_CH) * C_CH + g2];
            }
            unsigned h0 = f2bf_bits(w0), h1 = f2bf_bits(w1);
            float hf0 = __builtin_bit_cast(float, h0 << 16);
            float hf1 = __builtin_bit_cast(float, h1 << 16);
            unsigned l0 = f2bf_bits(w0 - hf0), l1 = f2bf_bits(w1 - hf1);
            *(unsigned*)&Wh[c][k] = h0 | (h1 << 16);
            *(unsigned*)&Wl[c][k] = l0 | (l1 << 16);
        }
        __syncthreads();
        int lane = tid & 63, wv = tid >> 6;
        int r0 = bx * 64 + wv * 16;
        int arow = min(r0 + (lane & 15), Nn - 1);
        int kgrp = (lane >> 4) * 8;
        f32x4 acc[4] = {};
#pragma unroll
        for (int kk = 0; kk < 4; ++kk) {
            int k0 = kk * 32 + kgrp;
            const float* xp = &x[(size_t)arow * C_CH + k0];
            float4 v0 = *(const float4*)xp;
            float4 v1 = *(const float4*)(xp + 4);
            float vv[8] = {v0.x, v0.y, v0.z, v0.w, v1.x, v1.y, v1.z, v1.w};
            bf16x8 ah, al;
#pragma unroll
            for (int u = 0; u < 8; ++u) {
                unsigned hb = f2bf_bits(vv[u]);
                float hf = __builtin_bit_cast(float, hb << 16);
                ah[u] = (short)hb;
                al[u] = (short)f2bf_bits(vv[u] - hf);
            }
#pragma unroll
            for (int j = 0; j < 4; ++j) {
                int c = j * 16 + (lane & 15);
                bf16x8 bh = *(const bf16x8*)&Wh[c][k0];
                bf16x8 bl = *(const bf16x8*)&Wl[c][k0];
                acc[j] = __builtin_amdgcn_mfma_f32_16x16x32_bf16(ah, bh, acc[j], 0, 0, 0);
                acc[j] = __builtin_amdgcn_mfma_f32_16x16x32_bf16(al, bh, acc[j], 0, 0, 0);
                acc[j] = __builtin_amdgcn_mfma_f32_16x16x32_bf16(ah, bl, acc[j], 0, 0, 0);
            }
        }
#pragma unroll
        for (int j = 0; j < 4; ++j) {
            int gc = col0 + j * 16 + (lane & 15);
            float badd = isA ? bias[gc] : 0.f;
#pragma unroll
            for (int reg = 0; reg < 4; ++reg) {
                int row = r0 + (lane >> 4) * 4 + reg;  // C/D: col=lane&15, row=(lane>>4)*4+reg
                if (row < Nn) {
                    if (isA) Aarr[(size_t)row * C_CH + gc] = acc[j][reg] + badd;
                    else     Bbf[(size_t)row * C_CH + (gc - C_CH)] =
                                 (unsigned short)f2bf_bits(acc[j][reg]);
                }
            }
        }
    } else {
        // ---------- bucket histogram (runs concurrently with GEMM blocks) ----------
        int b = bid - GX * 4;
        int NBq = (Nn + NPB - 1) >> BSH;
        for (int i = tid; i < BPAD; i += 256) cnt[i] = 0;
        __syncthreads();
        int e0 = b * chunk, e1 = min(e0 + chunk, E_);
        int n4 = (e1 - e0) >> 2;
        const int4* d4p = (const int4*)(dst + e0);
        for (int i = tid; i < n4; i += 256) {
            int4 d = d4p[i];
            atomicAdd(&cnt[d.x >> BSH], 1); atomicAdd(&cnt[d.y >> BSH], 1);
            atomicAdd(&cnt[d.z >> BSH], 1); atomicAdd(&cnt[d.w >> BSH], 1);
        }
        for (int i = e0 + n4 * 4 + tid; i < e1; i += 256) atomicAdd(&cnt[dst[i] >> BSH], 1);
        __syncthreads();
        int* Tb = T2 + (size_t)b * BPAD;
        for (int i = tid; i < NBq; i += 256) Tb[i] = cnt[i];
    }
}

// ---- K2: column scan of T2 + tail-fused scan(deg2)->offs2 (last-block pattern) ----
__global__ __launch_bounds__(256) void colscan_scan_k(int* __restrict__ T2,
                                                      int* __restrict__ deg2,
                                                      int* __restrict__ offs2,
                                                      int* __restrict__ done, int NBq) {
    __shared__ int wsum[4];
    __shared__ int amLast;
    int tid = threadIdx.x;
    int lane = tid & 63;
    int q = blockIdx.x * 4 + (tid >> 6);
    if (q < NBq) {
        int e[4], p[4];
#pragma unroll
        for (int k = 0; k < 4; ++k) e[k] = T2[(size_t)(lane + 64 * k) * BPAD + q];
        int s = 0;
#pragma unroll
        for (int k = 0; k < 4; ++k) { p[k] = s; s += e[k]; }
        int incl = s;
#pragma unroll
        for (int off = 1; off < 64; off <<= 1) {
            int t = __shfl_up(incl, off);
            if (lane >= off) incl += t;
        }
        int excl = incl - s;
#pragma unroll
        for (int k = 0; k < 4; ++k) T2[(size_t)(lane + 64 * k) * BPAD + q] = excl + p[k];
        if (lane == 63) deg2[q] = incl;  // lane 63 inclusive prefix == bucket total (R11 fix)
    }
    __syncthreads();
    if (tid == 0) {
        __threadfence();  // release deg2/T2 writes (device scope)
        amLast = (atomicAdd(done, 1) == (int)gridDim.x - 1);
    }
    __syncthreads();
    if (!amLast) return;
    __threadfence();  // acquire other blocks' deg2
    // in-block exclusive scan: 256 thr x PER=10 covers 2560 >= NBq+1
    const int PER = 10;
    int base = tid * PER;
    int v[PER];
    int s = 0;
#pragma unroll
    for (int k = 0; k < PER; ++k) {
        int idx = base + k;
        v[k] = (idx < NBq) ? deg2[idx] : 0;
        s += v[k];
    }
    int wid = tid >> 6;
    int pref = s;
#pragma unroll
    for (int off = 1; off < 64; off <<= 1) {
        int t = __shfl_up(pref, off);
        if (lane >= off) pref += t;
    }
    if (lane == 63) wsum[wid] = pref;
    __syncthreads();
    if (tid < 4) {
        int vv = wsum[tid];
#pragma unroll
        for (int off = 1; off < 4; off <<= 1) {
            int t = __shfl_up(vv, off, 4);
            if (tid >= off) vv += t;
        }
        wsum[tid] = vv;
    }
    __syncthreads();
    int run = ((wid > 0) ? wsum[wid - 1] : 0) + (pref - s);
#pragma unroll
    for (int k = 0; k < PER; ++k) {
        int idx = base + k;
        if (idx < NBq) offs2[idx] = run;
        run += v[k];
    }
    if (tid == 255) offs2[NBq] = run;
}

// ---- K3: scatter packed (src<<BSH | local) into bucket order ----
__global__ __launch_bounds__(256) void scatter2_k(const int* __restrict__ src,
                                                  const int* __restrict__ dst,
                                                  const int* __restrict__ T2,
                                                  const int* __restrict__ offs2,
                                                  unsigned* __restrict__ epack,
                                                  int E_, int NBq, int chunk) {
    __shared__ int sbase[BPAD];
    __shared__ int cur[BPAD];
    int tid = threadIdx.x, b = blockIdx.x;
    const int* Tb = T2 + (size_t)b * BPAD;
    for (int i = tid; i < NBq; i += 256) {
        sbase[i] = offs2[i] + Tb[i];
        cur[i] = 0;
    }
    __syncthreads();
    int e0 = b * chunk, e1 = min(e0 + chunk, E_);
    int n4 = (e1 - e0) >> 2;
    const int4* d4p = (const int4*)(dst + e0);
    const int4* s4p = (const int4*)(src + e0);
    const int LM = NPB - 1;
    for (int i = tid; i < n4; i += 256) {
        int4 d = d4p[i];
        int4 sv = s4p[i];
        int q, r;
        q = d.x >> BSH; r = atomicAdd(&cur[q], 1);
        epack[sbase[q] + r] = ((unsigned)sv.x << BSH) | (unsigned)(d.x & LM);
        q = d.y >> BSH; r = atomicAdd(&cur[q], 1);
        epack[sbase[q] + r] = ((unsigned)sv.y << BSH) | (unsigned)(d.y & LM);
        q = d.z >> BSH; r = atomicAdd(&cur[q], 1);
        epack[sbase[q] + r] = ((unsigned)sv.z << BSH) | (unsigned)(d.z & LM);
        q = d.w >> BSH; r = atomicAdd(&cur[q], 1);
        epack[sbase[q] + r] = ((unsigned)sv.w << BSH) | (unsigned)(d.w & LM);
    }
    for (int i = e0 + n4 * 4 + tid; i < e1; i += 256) {
        int d = dst[i];
        int q = d >> BSH;
        int r = atomicAdd(&cur[q], 1);
        epack[sbase[q] + r] = ((unsigned)src[i] << BSH) | (unsigned)(d & LM);
    }
}

// ---- K4 v4: branchless per-bucket max. 256 thr = 4 waves; each wave keeps the
// bucket's 4 node-accs in registers (lane = channels 2l,2l+1 packed); edge ids
// broadcast via uniform ds_read_b128 + readfirstlane; masked pkmax selection.
__global__ __launch_bounds__(256) void bucket_max(const float* __restrict__ Aarr,
                                                  const unsigned short* __restrict__ Bbf,
                                                  const int* __restrict__ offs2,
                                                  const unsigned* __restrict__ epack,
                                                  float* __restrict__ out, int Nn) {
    int q = blockIdx.x;
    int n0 = q << BSH;
    if (n0 >= Nn) return;
    __shared__ unsigned estage[CHK];      // 8KB
    __shared__ unsigned macc[4][NPB][64]; // 4KB
    int tid = threadIdx.x;
    int lane = tid & 63, w = tid >> 6;
    int s = offs2[q], e = offs2[q + 1];

    unsigned a0 = 0u, a1 = 0u, a2 = 0u, a3 = 0u;  // key 0 == "no edge"

    for (int c0 = s; c0 < e; c0 += CHK) {
        int ccnt = min(CHK, e - c0);
        int pad4 = (ccnt + 3) & ~3;
        for (int i = tid; i < pad4; i += 256)
            estage[i] = epack[c0 + min(i, ccnt - 1)];  // pad dups real edge: max-safe
        __syncthreads();
        int ng = pad4 >> 2;
        for (int g = w; g < ng; g += 4) {
            u32x4 pv = *(const u32x4*)&estage[4 * g];  // uniform 16B broadcast
            unsigned p0 = __builtin_amdgcn_readfirstlane(pv[0]);
            unsigned p1 = __builtin_amdgcn_readfirstlane(pv[1]);
            unsigned p2 = __builtin_amdgcn_readfirstlane(pv[2]);
            unsigned p3 = __builtin_amdgcn_readfirstlane(pv[3]);
            unsigned v0 = *(const unsigned*)&Bbf[(size_t)(p0 >> BSH) * C_CH + 2 * lane];
            unsigned v1 = *(const unsigned*)&Bbf[(size_t)(p1 >> BSH) * C_CH + 2 * lane];
            unsigned v2 = *(const unsigned*)&Bbf[(size_t)(p2 >> BSH) * C_CH + 2 * lane];
            unsigned v3 = *(const unsigned*)&Bbf[(size_t)(p3 >> BSH) * C_CH + 2 * lane];
            upd4(p0, v0, a0, a1, a2, a3);
            upd4(p1, v1, a0, a1, a2, a3);
            upd4(p2, v2, a0, a1, a2, a3);
            upd4(p3, v3, a0, a1, a2, a3);
        }
        __syncthreads();  // protect estage before next chunk overwrite
    }

    macc[w][0][lane] = a0;
    macc[w][1][lane] = a1;
    macc[w][2][lane] = a2;
    macc[w][3][lane] = a3;
    __syncthreads();
    // merge 4 waves + epilogue: 4 nodes x 64 lane-channels = 256 slots = tid
    int loc = tid >> 6, ln = tid & 63;
    unsigned m = macc[0][loc][ln];
#pragma unroll
    for (int ww = 1; ww < 4; ++ww) m = pkmax(m, macc[ww][loc][ln]);
    int row = n0 + loc;
    if (row < Nn) {
        float2 o = make_float2(0.f, 0.f);
        if (m != 0u) {  // node had >=1 edge
            unsigned t = (m >> 15) & 0x00010001u;
            unsigned h = m ^ (0xFFFFFFFFu - t * 0x7FFFu);  // decode keys -> bf16 bits
            float blo = __builtin_bit_cast(float, (h & 0xFFFFu) << 16);
            float bhi = __builtin_bit_cast(float, h & 0xFFFF0000u);
            const float2 av = *(const float2*)&Aarr[(size_t)row * C_CH + 2 * ln];
            o.x = fmaxf(av.x + blo, 0.f);
            o.y = fmaxf(av.y + bhi, 0.f);
        }
        *(float2*)&out[(size_t)row * C_CH + 2 * ln] = o;
    }
}

extern "C" void kernel_launch(void* const* d_in, const int* in_sizes, int n_in,
                              void* d_out, int out_size, void* d_ws, size_t ws_size,
                              hipStream_t stream) {
    const float* x = (const float*)d_in[0];   // [N,128]
    const float* W = (const float*)d_in[1];   // [256,128]
    const float* b = (const float*)d_in[2];   // [128]
    const int* src = (const int*)d_in[3];     // [E]
    const int* dst = (const int*)d_in[4];     // [E]
    float* out = (float*)d_out;

    const int N = in_sizes[0] / C_CH;
    const int E = in_sizes[3];
    const int NBq = (N + NPB - 1) >> BSH;
    const int chunk = (((E + HBLK - 1) / HBLK) + 3) & ~3;
    const int GX = (N + 63) >> 6;

    char* w = (char*)d_ws;
    float* Aarr = (float*)w;                   w += align_up((size_t)N * C_CH * 4, 256);
    unsigned short* Bbf = (unsigned short*)w;  w += align_up((size_t)N * C_CH * 2, 256);
    int* deg2 = (int*)w;                       w += align_up((size_t)BPAD * 4, 256);
    int* offs2 = (int*)w;                      w += align_up((size_t)(BPAD + 1) * 4, 256);
    int* T2 = (int*)w;                         w += align_up((size_t)HBLK * BPAD * 4, 256);
    unsigned* epack = (unsigned*)w;            w += align_up((size_t)E * 4, 256);
    int* done = (int*)w;                       w += 256;

    hipMemsetAsync(done, 0, 4, stream);

    gemm_hist<<<GX * 4 + HBLK, 256, 0, stream>>>(x, W, b, Aarr, Bbf, dst, T2, N, E, chunk);
    colscan_scan_k<<<(NBq + 3) / 4, 256, 0, stream>>>(T2, deg2, offs2, done, NBq);
    scatter2_k<<<HBLK, 256, 0, stream>>>(src, dst, T2, offs2, epack, E, NBq, chunk);
    bucket_max<<<NBq, 256, 0, stream>>>(Aarr, Bbf, offs2, epack, out, N);
}

// Round 14
// 122.567 us; speedup vs baseline: 1.3098x; 1.3098x over previous
//
#include <hip/hip_runtime.h>
#include <cstdint>

// EdgeConv on MI355X.
// msg_e = A[dst] + B[src], A = x@(W1-W2)+b, B = x@W2.
// agg[i] = A[i] + max_{e: dst=i} B[src_e];  out = relu(agg), 0 for isolated nodes.
// GEMM: bf16x3 MFMA + fused bucket histogram (split-grid).
// Bucket CSR, 4-node buckets.  bucket_max v4: branchless masked pkmax  [R13 OK]
// colscan v2 (this round): COALESCED two-pass chunk scan (R13 post-mortem:
// wave-per-bucket gather at BPAD=2560 = 10KB lane stride -> transaction-bound,
// 49.6us @ 575GB/s effective. Lane must map to consecutive buckets.)

#define C_CH 128
#define HBLK 256          // histogram/scatter blocks == T2 rows
#define BSH 2             // nodes per bucket = 4
#define NPB 4             // 1<<BSH
#define BPAD 2560         // padded bucket count (>= NBq = 2500)
#define CHK 2048          // edge-stage chunk in bucket_max

typedef __attribute__((ext_vector_type(8))) short bf16x8;
typedef __attribute__((ext_vector_type(4))) float f32x4;
typedef __attribute__((ext_vector_type(4))) unsigned int u32x4;
typedef __attribute__((ext_vector_type(2))) unsigned short u16x2v;

static inline size_t align_up(size_t v, size_t a) { return (v + a - 1) & ~(a - 1); }

__device__ inline unsigned f2bf_bits(float f) {  // RNE float->bf16 bits
    unsigned u = __builtin_bit_cast(unsigned, f);
    return (u + 0x7FFFu + ((u >> 16) & 1u)) >> 16;
}
__device__ inline unsigned pkmax(unsigned a, unsigned b) {
    u16x2v av = __builtin_bit_cast(u16x2v, a), bv = __builtin_bit_cast(u16x2v, b);
    return __builtin_bit_cast(unsigned, __builtin_elementwise_max(av, bv));
}
// branchless: key masked to 0 (max-identity) unless edge targets node k.
// p is wave-uniform (from readfirstlane) -> masks are SGPR cselects.
__device__ inline void upd4(unsigned p, unsigned v,
                            unsigned& a0, unsigned& a1, unsigned& a2, unsigned& a3) {
    unsigned sgn = (v >> 15) & 0x00010001u;
    unsigned key = v ^ (0x80008000u | (sgn * 0x7FFFu));
    unsigned loc = p & (NPB - 1);
    unsigned m0 = (loc == 0) ? 0xFFFFFFFFu : 0u;
    unsigned m1 = (loc == 1) ? 0xFFFFFFFFu : 0u;
    unsigned m2 = (loc == 2) ? 0xFFFFFFFFu : 0u;
    unsigned m3 = (loc == 3) ? 0xFFFFFFFFu : 0u;
    a0 = pkmax(a0, key & m0);
    a1 = pkmax(a1, key & m1);
    a2 = pkmax(a2, key & m2);
    a3 = pkmax(a3, key & m3);
}

// ---- K1: split-grid: [0, GX*4) MFMA GEMM blocks; [GX*4, +HBLK) bucket hist ----
__global__ __launch_bounds__(256) void gemm_hist(const float* __restrict__ x,
                                                 const float* __restrict__ W,
                                                 const float* __restrict__ bias,
                                                 float* __restrict__ Aarr,
                                                 unsigned short* __restrict__ Bbf,
                                                 const int* __restrict__ dst,
                                                 int* __restrict__ T2,
                                                 int Nn, int E_, int chunk) {
    __shared__ unsigned short Wh[64][136];
    __shared__ unsigned short Wl[64][136];
    __shared__ int cnt[BPAD];
    int tid = threadIdx.x;
    int GX = (Nn + 63) >> 6;
    int bid = blockIdx.x;
    if (bid < GX * 4) {
        // ---------- GEMM (proven R7-R13) ----------
        int bx = bid % GX, by = bid / GX;
        int col0 = by * 64;
        bool isA = (col0 < C_CH);  // block-uniform
        for (int idx = tid; idx < 64 * 64; idx += 256) {
            int c = idx & 63, k = (idx >> 6) * 2;
            int gc = col0 + c;
            float w0, w1;
            if (isA) {
                w0 = W[k * C_CH + gc] - W[(k + C_CH) * C_CH + gc];
                w1 = W[(k + 1) * C_CH + gc] - W[(k + 1 + C_CH) * C_CH + gc];
            } else {
                int g2 = gc - C_CH;
                w0 = W[(k + C_CH) * C_CH + g2];
                w1 = W[(k + 1 + C_CH) * C_CH + g2];
            }
            unsigned h0 = f2bf_bits(w0), h1 = f2bf_bits(w1);
            float hf0 = __builtin_bit_cast(float, h0 << 16);
            float hf1 = __builtin_bit_cast(float, h1 << 16);
            unsigned l0 = f2bf_bits(w0 - hf0), l1 = f2bf_bits(w1 - hf1);
            *(unsigned*)&Wh[c][k] = h0 | (h1 << 16);
            *(unsigned*)&Wl[c][k] = l0 | (l1 << 16);
        }
        __syncthreads();
        int lane = tid & 63, wv = tid >> 6;
        int r0 = bx * 64 + wv * 16;
        int arow = min(r0 + (lane & 15), Nn - 1);
        int kgrp = (lane >> 4) * 8;
        f32x4 acc[4] = {};
#pragma unroll
        for (int kk = 0; kk < 4; ++kk) {
            int k0 = kk * 32 + kgrp;
            const float* xp = &x[(size_t)arow * C_CH + k0];
            float4 v0 = *(const float4*)xp;
            float4 v1 = *(const float4*)(xp + 4);
            float vv[8] = {v0.x, v0.y, v0.z, v0.w, v1.x, v1.y, v1.z, v1.w};
            bf16x8 ah, al;
#pragma unroll
            for (int u = 0; u < 8; ++u) {
                unsigned hb = f2bf_bits(vv[u]);
                float hf = __builtin_bit_cast(float, hb << 16);
                ah[u] = (short)hb;
                al[u] = (short)f2bf_bits(vv[u] - hf);
            }
#pragma unroll
            for (int j = 0; j < 4; ++j) {
                int c = j * 16 + (lane & 15);
                bf16x8 bh = *(const bf16x8*)&Wh[c][k0];
                bf16x8 bl = *(const bf16x8*)&Wl[c][k0];
                acc[j] = __builtin_amdgcn_mfma_f32_16x16x32_bf16(ah, bh, acc[j], 0, 0, 0);
                acc[j] = __builtin_amdgcn_mfma_f32_16x16x32_bf16(al, bh, acc[j], 0, 0, 0);
                acc[j] = __builtin_amdgcn_mfma_f32_16x16x32_bf16(ah, bl, acc[j], 0, 0, 0);
            }
        }
#pragma unroll
        for (int j = 0; j < 4; ++j) {
            int gc = col0 + j * 16 + (lane & 15);
            float badd = isA ? bias[gc] : 0.f;
#pragma unroll
            for (int reg = 0; reg < 4; ++reg) {
                int row = r0 + (lane >> 4) * 4 + reg;  // C/D: col=lane&15, row=(lane>>4)*4+reg
                if (row < Nn) {
                    if (isA) Aarr[(size_t)row * C_CH + gc] = acc[j][reg] + badd;
                    else     Bbf[(size_t)row * C_CH + (gc - C_CH)] =
                                 (unsigned short)f2bf_bits(acc[j][reg]);
                }
            }
        }
    } else {
        // ---------- bucket histogram (runs concurrently with GEMM blocks) ----------
        int b = bid - GX * 4;
        int NBq = (Nn + NPB - 1) >> BSH;
        for (int i = tid; i < BPAD; i += 256) cnt[i] = 0;
        __syncthreads();
        int e0 = b * chunk, e1 = min(e0 + chunk, E_);
        int n4 = (e1 - e0) >> 2;
        const int4* d4p = (const int4*)(dst + e0);
        for (int i = tid; i < n4; i += 256) {
            int4 d = d4p[i];
            atomicAdd(&cnt[d.x >> BSH], 1); atomicAdd(&cnt[d.y >> BSH], 1);
            atomicAdd(&cnt[d.z >> BSH], 1); atomicAdd(&cnt[d.w >> BSH], 1);
        }
        for (int i = e0 + n4 * 4 + tid; i < e1; i += 256) atomicAdd(&cnt[dst[i] >> BSH], 1);
        __syncthreads();
        int* Tb = T2 + (size_t)b * BPAD;
        for (int i = tid; i < NBq; i += 256) Tb[i] = cnt[i];
    }
}

// ---- K2 v2: COALESCED column scan of T2 + tail-fused scan(deg2)->offs2 ----
// Block g owns 64 consecutive buckets (lane = bucket g*64+lane -> 256B/row
// coalesced). 4 waves x 64-row chunks; pass1 chunk sums, pass2 writeback.
__global__ __launch_bounds__(256) void colscan_scan_k(int* __restrict__ T2,
                                                      int* __restrict__ deg2,
                                                      int* __restrict__ offs2,
                                                      int* __restrict__ done, int NBq) {
    __shared__ int csum[4][64];
    __shared__ int wsum[4];
    __shared__ int amLast;
    int tid = threadIdx.x;
    int lane = tid & 63, w = tid >> 6;
    int q = blockIdx.x * 64 + lane;
    bool valid = (q < NBq);
    // pass 1: chunk sums (rows w*64 .. w*64+63), coalesced loads
    int s = 0;
    if (valid) {
#pragma unroll 8
        for (int b = w * 64; b < w * 64 + 64; ++b) s += T2[(size_t)b * BPAD + q];
    }
    csum[w][lane] = s;
    __syncthreads();
    int base = 0;
#pragma unroll
    for (int ww = 0; ww < 4; ++ww) {
        int c = csum[ww][lane];
        if (ww < w) base += c;
    }
    int total = csum[0][lane] + csum[1][lane] + csum[2][lane] + csum[3][lane];
    // pass 2: exclusive write-back within chunk (rows L2-hot from pass 1)
    if (valid) {
        int run = base;
#pragma unroll 8
        for (int b = w * 64; b < w * 64 + 64; ++b) {
            int v = T2[(size_t)b * BPAD + q];
            T2[(size_t)b * BPAD + q] = run;
            run += v;
        }
        if (w == 0) deg2[q] = total;
    }
    __syncthreads();
    if (tid == 0) {
        __threadfence();  // release deg2/T2 writes (device scope)
        amLast = (atomicAdd(done, 1) == (int)gridDim.x - 1);
    }
    __syncthreads();
    if (!amLast) return;
    __threadfence();  // acquire other blocks' deg2
    // in-block exclusive scan: 256 thr x PER=10 covers 2560 >= NBq+1
    const int PER = 10;
    int base0 = tid * PER;
    int v[PER];
    int ssum = 0;
#pragma unroll
    for (int k = 0; k < PER; ++k) {
        int idx = base0 + k;
        v[k] = (idx < NBq) ? deg2[idx] : 0;
        ssum += v[k];
    }
    int wid = tid >> 6;
    int pref = ssum;
#pragma unroll
    for (int off = 1; off < 64; off <<= 1) {
        int t = __shfl_up(pref, off);
        if (lane >= off) pref += t;
    }
    if (lane == 63) wsum[wid] = pref;
    __syncthreads();
    if (tid < 4) {
        int vv = wsum[tid];
#pragma unroll
        for (int off = 1; off < 4; off <<= 1) {
            int t = __shfl_up(vv, off, 4);
            if (tid >= off) vv += t;
        }
        wsum[tid] = vv;
    }
    __syncthreads();
    int run = ((wid > 0) ? wsum[wid - 1] : 0) + (pref - ssum);
#pragma unroll
    for (int k = 0; k < PER; ++k) {
        int idx = base0 + k;
        if (idx < NBq) offs2[idx] = run;
        run += v[k];
    }
    if (tid == 255) offs2[NBq] = run;
}

// ---- K3: scatter packed (src<<BSH | local) into bucket order ----
__global__ __launch_bounds__(256) void scatter2_k(const int* __restrict__ src,
                                                  const int* __restrict__ dst,
                                                  const int* __restrict__ T2,
                                                  const int* __restrict__ offs2,
                                                  unsigned* __restrict__ epack,
                                                  int E_, int NBq, int chunk) {
    __shared__ int sbase[BPAD];
    __shared__ int cur[BPAD];
    int tid = threadIdx.x, b = blockIdx.x;
    const int* Tb = T2 + (size_t)b * BPAD;
    for (int i = tid; i < NBq; i += 256) {
        sbase[i] = offs2[i] + Tb[i];
        cur[i] = 0;
    }
    __syncthreads();
    int e0 = b * chunk, e1 = min(e0 + chunk, E_);
    int n4 = (e1 - e0) >> 2;
    const int4* d4p = (const int4*)(dst + e0);
    const int4* s4p = (const int4*)(src + e0);
    const int LM = NPB - 1;
    for (int i = tid; i < n4; i += 256) {
        int4 d = d4p[i];
        int4 sv = s4p[i];
        int q, r;
        q = d.x >> BSH; r = atomicAdd(&cur[q], 1);
        epack[sbase[q] + r] = ((unsigned)sv.x << BSH) | (unsigned)(d.x & LM);
        q = d.y >> BSH; r = atomicAdd(&cur[q], 1);
        epack[sbase[q] + r] = ((unsigned)sv.y << BSH) | (unsigned)(d.y & LM);
        q = d.z >> BSH; r = atomicAdd(&cur[q], 1);
        epack[sbase[q] + r] = ((unsigned)sv.z << BSH) | (unsigned)(d.z & LM);
        q = d.w >> BSH; r = atomicAdd(&cur[q], 1);
        epack[sbase[q] + r] = ((unsigned)sv.w << BSH) | (unsigned)(d.w & LM);
    }
    for (int i = e0 + n4 * 4 + tid; i < e1; i += 256) {
        int d = dst[i];
        int q = d >> BSH;
        int r = atomicAdd(&cur[q], 1);
        epack[sbase[q] + r] = ((unsigned)src[i] << BSH) | (unsigned)(d & LM);
    }
}

// ---- K4 v4: branchless per-bucket max. 256 thr = 4 waves; each wave keeps the
// bucket's 4 node-accs in registers (lane = channels 2l,2l+1 packed); edge ids
// broadcast via uniform ds_read_b128 + readfirstlane; masked pkmax selection.
__global__ __launch_bounds__(256) void bucket_max(const float* __restrict__ Aarr,
                                                  const unsigned short* __restrict__ Bbf,
                                                  const int* __restrict__ offs2,
                                                  const unsigned* __restrict__ epack,
                                                  float* __restrict__ out, int Nn) {
    int q = blockIdx.x;
    int n0 = q << BSH;
    if (n0 >= Nn) return;
    __shared__ unsigned estage[CHK];      // 8KB
    __shared__ unsigned macc[4][NPB][64]; // 4KB
    int tid = threadIdx.x;
    int lane = tid & 63, w = tid >> 6;
    int s = offs2[q], e = offs2[q + 1];

    unsigned a0 = 0u, a1 = 0u, a2 = 0u, a3 = 0u;  // key 0 == "no edge"

    for (int c0 = s; c0 < e; c0 += CHK) {
        int ccnt = min(CHK, e - c0);
        int pad4 = (ccnt + 3) & ~3;
        for (int i = tid; i < pad4; i += 256)
            estage[i] = epack[c0 + min(i, ccnt - 1)];  // pad dups real edge: max-safe
        __syncthreads();
        int ng = pad4 >> 2;
        for (int g = w; g < ng; g += 4) {
            u32x4 pv = *(const u32x4*)&estage[4 * g];  // uniform 16B broadcast
            unsigned p0 = __builtin_amdgcn_readfirstlane(pv[0]);
            unsigned p1 = __builtin_amdgcn_readfirstlane(pv[1]);
            unsigned p2 = __builtin_amdgcn_readfirstlane(pv[2]);
            unsigned p3 = __builtin_amdgcn_readfirstlane(pv[3]);
            unsigned v0 = *(const unsigned*)&Bbf[(size_t)(p0 >> BSH) * C_CH + 2 * lane];
            unsigned v1 = *(const unsigned*)&Bbf[(size_t)(p1 >> BSH) * C_CH + 2 * lane];
            unsigned v2 = *(const unsigned*)&Bbf[(size_t)(p2 >> BSH) * C_CH + 2 * lane];
            unsigned v3 = *(const unsigned*)&Bbf[(size_t)(p3 >> BSH) * C_CH + 2 * lane];
            upd4(p0, v0, a0, a1, a2, a3);
            upd4(p1, v1, a0, a1, a2, a3);
            upd4(p2, v2, a0, a1, a2, a3);
            upd4(p3, v3, a0, a1, a2, a3);
        }
        __syncthreads();  // protect estage before next chunk overwrite
    }

    macc[w][0][lane] = a0;
    macc[w][1][lane] = a1;
    macc[w][2][lane] = a2;
    macc[w][3][lane] = a3;
    __syncthreads();
    // merge 4 waves + epilogue: 4 nodes x 64 lane-channels = 256 slots = tid
    int loc = tid >> 6, ln = tid & 63;
    unsigned m = macc[0][loc][ln];
#pragma unroll
    for (int ww = 1; ww < 4; ++ww) m = pkmax(m, macc[ww][loc][ln]);
    int row = n0 + loc;
    if (row < Nn) {
        float2 o = make_float2(0.f, 0.f);
        if (m != 0u) {  // node had >=1 edge
            unsigned t = (m >> 15) & 0x00010001u;
            unsigned h = m ^ (0xFFFFFFFFu - t * 0x7FFFu);  // decode keys -> bf16 bits
            float blo = __builtin_bit_cast(float, (h & 0xFFFFu) << 16);
            float bhi = __builtin_bit_cast(float, h & 0xFFFF0000u);
            const float2 av = *(const float2*)&Aarr[(size_t)row * C_CH + 2 * ln];
            o.x = fmaxf(av.x + blo, 0.f);
            o.y = fmaxf(av.y + bhi, 0.f);
        }
        *(float2*)&out[(size_t)row * C_CH + 2 * ln] = o;
    }
}

extern "C" void kernel_launch(void* const* d_in, const int* in_sizes, int n_in,
                              void* d_out, int out_size, void* d_ws, size_t ws_size,
                              hipStream_t stream) {
    const float* x = (const float*)d_in[0];   // [N,128]
    const float* W = (const float*)d_in[1];   // [256,128]
    const float* b = (const float*)d_in[2];   // [128]
    const int* src = (const int*)d_in[3];     // [E]
    const int* dst = (const int*)d_in[4];     // [E]
    float* out = (float*)d_out;

    const int N = in_sizes[0] / C_CH;
    const int E = in_sizes[3];
    const int NBq = (N + NPB - 1) >> BSH;
    const int chunk = (((E + HBLK - 1) / HBLK) + 3) & ~3;
    const int GX = (N + 63) >> 6;

    char* w = (char*)d_ws;
    float* Aarr = (float*)w;                   w += align_up((size_t)N * C_CH * 4, 256);
    unsigned short* Bbf = (unsigned short*)w;  w += align_up((size_t)N * C_CH * 2, 256);
    int* deg2 = (int*)w;                       w += align_up((size_t)BPAD * 4, 256);
    int* offs2 = (int*)w;                      w += align_up((size_t)(BPAD + 1) * 4, 256);
    int* T2 = (int*)w;                         w += align_up((size_t)HBLK * BPAD * 4, 256);
    unsigned* epack = (unsigned*)w;            w += align_up((size_t)E * 4, 256);
    int* done = (int*)w;                       w += 256;

    hipMemsetAsync(done, 0, 4, stream);

    gemm_hist<<<GX * 4 + HBLK, 256, 0, stream>>>(x, W, b, Aarr, Bbf, dst, T2, N, E, chunk);
    colscan_scan_k<<<(NBq + 63) / 64, 256, 0, stream>>>(T2, deg2, offs2, done, NBq);
    scatter2_k<<<HBLK, 256, 0, stream>>>(src, dst, T2, offs2, epack, E, NBq, chunk);
    bucket_max<<<NBq, 256, 0, stream>>>(Aarr, Bbf, offs2, epack, out, N);
}